// Round 2
// baseline (496.326 us; speedup 1.0000x reference)
//
#include <hip/hip_runtime.h>

#define NTOK 4096
#define DIM  1024
#define NEXP 8
#define HDIM 2048
#define CAP  9216   // 2*NTOK assignments + 8*128 alignment padding

typedef unsigned short u16;
typedef __attribute__((ext_vector_type(8))) __bf16 bf16x8;
typedef __attribute__((ext_vector_type(4))) float  f32x4;
typedef __attribute__((ext_vector_type(8))) u16    u16x8;

__device__ inline u16 f2bf(float f) {
    union { float f; unsigned u; } v; v.f = f;
    unsigned r = v.u + 0x7fff + ((v.u >> 16) & 1);   // RNE
    return (u16)(r >> 16);
}

__device__ inline void gload_lds16(const void* g, void* l) {
    __builtin_amdgcn_global_load_lds(
        (const __attribute__((address_space(1))) unsigned int*)g,
        (__attribute__((address_space(3))) unsigned int*)l, 16, 0, 0);
}

// ---------------- fp32 -> bf16 convert (vectorized, grid-stride) ----------------
__global__ __launch_bounds__(256) void cvt_kernel(const float* __restrict__ in,
                                                  u16* __restrict__ out, int n8) {
    int stride = gridDim.x * 256;
    for (int i = blockIdx.x * 256 + threadIdx.x; i < n8; i += stride) {
        float4 a = ((const float4*)in)[(size_t)i * 2];
        float4 b = ((const float4*)in)[(size_t)i * 2 + 1];
        u16x8 v;
        v[0]=f2bf(a.x); v[1]=f2bf(a.y); v[2]=f2bf(a.z); v[3]=f2bf(a.w);
        v[4]=f2bf(b.x); v[5]=f2bf(b.y); v[6]=f2bf(b.z); v[7]=f2bf(b.w);
        ((u16x8*)out)[i] = v;
    }
}

// ---------------- gate: fp32 logits, softmax, top2, loss partials ----------------
__global__ __launch_bounds__(256) void gate_kernel(
    const float* __restrict__ x, const unsigned char* __restrict__ pm,
    const float* __restrict__ gw, float* __restrict__ gate_out,
    int* __restrict__ tok_e, float* __restrict__ tok_w,
    int* __restrict__ counts, float* __restrict__ gv_sum,
    float* __restrict__ top1c, float* __restrict__ nt_acc) {
    __shared__ float lgw[NEXP * DIM];
    __shared__ float bgv[NEXP];
    __shared__ float bt1[NEXP];
    __shared__ int   bcnt[NEXP];
    __shared__ float bnt;
    int t = threadIdx.x;
    for (int k = t; k < NEXP * DIM / 4; k += 256)
        ((float4*)lgw)[k] = ((const float4*)gw)[k];
    if (t < NEXP) { bgv[t] = 0.f; bt1[t] = 0.f; bcnt[t] = 0; }
    if (t == 0) bnt = 0.f;
    __syncthreads();

    int lane = t & 63, wv = t >> 6;
    for (int i = 0; i < 4; ++i) {
        int tok = blockIdx.x * 16 + wv * 4 + i;
        float acc[NEXP];
#pragma unroll
        for (int e = 0; e < NEXP; ++e) acc[e] = 0.f;
        const float* xr = x + (size_t)tok * DIM;
        for (int j = lane; j < DIM; j += 64) {
            float xv = xr[j];
#pragma unroll
            for (int e = 0; e < NEXP; ++e) acc[e] += xv * lgw[e * DIM + j];
        }
#pragma unroll
        for (int e = 0; e < NEXP; ++e) {
            float s = acc[e];
            for (int off = 1; off < 64; off <<= 1) s += __shfl_xor(s, off);
            acc[e] = s;
        }
        if (lane == 0) {
            bool padded = pm[tok] != 0;
            float m = acc[0];
            for (int e = 1; e < NEXP; ++e) m = fmaxf(m, acc[e]);
            float ex[NEXP]; float ssum = 0.f;
            for (int e = 0; e < NEXP; ++e) { ex[e] = expf(acc[e] - m); ssum += ex[e]; }
            float inv = 1.f / ssum;
            float gv[NEXP];
            for (int e = 0; e < NEXP; ++e) gv[e] = padded ? 0.f : ex[e] * inv;
            for (int e = 0; e < NEXP; ++e) gate_out[(size_t)tok * NEXP + e] = gv[e];
            // top-2, first-index-wins ties (matches lax.top_k)
            int t1 = 0;
            for (int e = 1; e < NEXP; ++e) if (gv[e] > gv[t1]) t1 = e;
            int t2 = (t1 == 0) ? 1 : 0;
            for (int e = 0; e < NEXP; ++e) { if (e == t1 || e == t2) continue; if (gv[e] > gv[t2]) t2 = e; }
            float w1 = gv[t1], w2 = gv[t2], den = w1 + w2;
            float invd = (den > 0.f) ? 1.f / den : 0.f;
            tok_e[tok * 2]     = t1;  tok_e[tok * 2 + 1] = t2;
            tok_w[tok * 2]     = w1 * invd;
            tok_w[tok * 2 + 1] = w2 * invd;
            atomicAdd(&bcnt[t1], 1); atomicAdd(&bcnt[t2], 1);
            if (!padded) {
                atomicAdd(&bt1[t1], 1.f); atomicAdd(&bnt, 1.f);
                for (int e = 0; e < NEXP; ++e) atomicAdd(&bgv[e], gv[e]);
            }
        }
    }
    __syncthreads();
    if (t < NEXP) {
        atomicAdd(&counts[t], bcnt[t]);
        atomicAdd(&gv_sum[t], bgv[t]);
        atomicAdd(&top1c[t],  bt1[t]);
    }
    if (t == 0) atomicAdd(nt_acc, bnt);
}

// scan (expert offsets) + lb_loss, fused (both depend only on gate_kernel)
__global__ void scan_loss_kernel(const int* __restrict__ counts, int* __restrict__ offsets,
                                 const float* __restrict__ gv_sum, const float* __restrict__ top1c,
                                 const float* __restrict__ nt_acc, float* __restrict__ lout) {
    if (threadIdx.x == 0 && blockIdx.x == 0) {
        int o = 0;
        for (int e = 0; e < NEXP; ++e) { offsets[e] = o; o += (counts[e] + 127) & ~127; }
        offsets[NEXP] = o;
        float nt = nt_acc[0];
        if (nt <= 0.f) nt = 1.f;
        float s = 0.f;
        for (int e = 0; e < NEXP; ++e) s += top1c[e] * gv_sum[e];
        lout[0] = NEXP * s / (nt * nt);
    }
}

__global__ __launch_bounds__(256) void scatter_kernel(
    const int* __restrict__ tok_e, const float* __restrict__ tok_w,
    const int* __restrict__ offsets, int* __restrict__ fill,
    int* __restrict__ tokens_l, float* __restrict__ gatew_l) {
    int tok = blockIdx.x * 256 + threadIdx.x;
    if (tok >= NTOK) return;
    for (int k = 0; k < 2; ++k) {
        int e = tok_e[tok * 2 + k];
        int p = atomicAdd(&fill[e], 1);
        int pos = offsets[e] + p;
        tokens_l[pos] = tok;
        gatew_l[pos]  = tok_w[tok * 2 + k];
    }
}

// ---------------- grouped GEMM: 128x128 tile, BK=64, 2-phase LDS double-buffer ----
// Block mapping: expert = blockIdx.x & 7 (low bits -> same XCD per expert, so the
// expert's 4MB weight panel stays resident in that XCD's L2). tn = blockIdx.x >> 3.
// EPI=1: C = relu(A_gathered @ B^T + bias) -> bf16 act      (K=1024, N=2048)
// EPI=2: out[token] += gatew * (A @ B^T + bias)             (K=2048, N=1024)
template <int EPI, int KDIM, int NDIM, int ASTRIDE>
__global__ __launch_bounds__(256, 2) void gemm_kernel(
    const u16* __restrict__ A, const u16* __restrict__ Bw,
    const float* __restrict__ bias,
    const int* __restrict__ tokens_l, const float* __restrict__ gatew_l,
    const int* __restrict__ counts, const int* __restrict__ offsets,
    u16* __restrict__ actout, float* __restrict__ out) {
    int e  = blockIdx.x & 7;
    int tn = blockIdx.x >> 3;
    int tm = blockIdx.y;
    int count = counts[e];
    if (tm * 128 >= count) return;
    int offs = offsets[e];

    __shared__ __align__(16) u16 lA[2][128 * 64];
    __shared__ __align__(16) u16 lB[2][128 * 64];

    int t = threadIdx.x, lane = t & 63;
    const u16* Ap[4]; const u16* Bp[4];
#pragma unroll
    for (int it = 0; it < 4; ++it) {
        int f = it * 256 + t;
        int row = f >> 3, c8 = f & 7;
        size_t arow;
        if (EPI == 1) arow = (size_t)tokens_l[offs + tm * 128 + row];
        else          arow = (size_t)(offs + tm * 128 + row);
        Ap[it] = A + arow * ASTRIDE + c8 * 8;
        Bp[it] = Bw + ((size_t)e * NDIM + tn * 128 + row) * KDIM + c8 * 8;
    }

    f32x4 acc[4][4];
#pragma unroll
    for (int i = 0; i < 4; ++i)
#pragma unroll
        for (int j = 0; j < 4; ++j) acc[i][j] = (f32x4)(0.f);

    int wm = (t >> 6) >> 1, wn = (t >> 6) & 1;
    int l16 = lane & 15, lq = lane >> 4;

    const int NKT = KDIM / 64;
    // prologue: stage tile 0 into buffer 0, drain
#pragma unroll
    for (int it = 0; it < 4; ++it) {
        gload_lds16(Ap[it], &lA[0][(it * 256 + t) * 8]);
        gload_lds16(Bp[it], &lB[0][(it * 256 + t) * 8]);
    }
    asm volatile("s_waitcnt vmcnt(0)" ::: "memory");
    __syncthreads();

    int cur = 0;
    for (int kt = 0; kt < NKT - 1; ++kt) {
        // issue next-tile loads into the other buffer (in flight under MFMA)
#pragma unroll
        for (int it = 0; it < 4; ++it) {
            gload_lds16(Ap[it] + (kt + 1) * 64, &lA[cur ^ 1][(it * 256 + t) * 8]);
            gload_lds16(Bp[it] + (kt + 1) * 64, &lB[cur ^ 1][(it * 256 + t) * 8]);
        }
        // compute current buffer
#pragma unroll
        for (int kk = 0; kk < 2; ++kk) {
            bf16x8 av[4], bv[4];
#pragma unroll
            for (int mi = 0; mi < 4; ++mi)
                av[mi] = *(const bf16x8*)&lA[cur][(wm * 64 + mi * 16 + l16) * 64 + kk * 32 + lq * 8];
#pragma unroll
            for (int ni = 0; ni < 4; ++ni)
                bv[ni] = *(const bf16x8*)&lB[cur][(wn * 64 + ni * 16 + l16) * 64 + kk * 32 + lq * 8];
#pragma unroll
            for (int mi = 0; mi < 4; ++mi)
#pragma unroll
                for (int ni = 0; ni < 4; ++ni)
                    acc[mi][ni] = __builtin_amdgcn_mfma_f32_16x16x32_bf16(av[mi], bv[ni], acc[mi][ni], 0, 0, 0);
        }
        asm volatile("s_waitcnt vmcnt(0)" ::: "memory");
        __syncthreads();
        cur ^= 1;
    }
    // epilogue tile: compute only
#pragma unroll
    for (int kk = 0; kk < 2; ++kk) {
        bf16x8 av[4], bv[4];
#pragma unroll
        for (int mi = 0; mi < 4; ++mi)
            av[mi] = *(const bf16x8*)&lA[cur][(wm * 64 + mi * 16 + l16) * 64 + kk * 32 + lq * 8];
#pragma unroll
        for (int ni = 0; ni < 4; ++ni)
            bv[ni] = *(const bf16x8*)&lB[cur][(wn * 64 + ni * 16 + l16) * 64 + kk * 32 + lq * 8];
#pragma unroll
        for (int mi = 0; mi < 4; ++mi)
#pragma unroll
            for (int ni = 0; ni < 4; ++ni)
                acc[mi][ni] = __builtin_amdgcn_mfma_f32_16x16x32_bf16(av[mi], bv[ni], acc[mi][ni], 0, 0, 0);
    }

    if (EPI == 1) {
#pragma unroll
        for (int ni = 0; ni < 4; ++ni) {
            int gcol = tn * 128 + wn * 64 + ni * 16 + l16;
            float bv_ = bias[e * NDIM + gcol];
#pragma unroll
            for (int mi = 0; mi < 4; ++mi)
#pragma unroll
                for (int r = 0; r < 4; ++r) {
                    int grow = tm * 128 + wm * 64 + mi * 16 + lq * 4 + r;
                    float v = acc[mi][ni][r] + bv_;
                    v = fmaxf(v, 0.f);
                    actout[(size_t)(offs + grow) * HDIM + gcol] = f2bf(v);
                }
        }
    } else {
#pragma unroll
        for (int mi = 0; mi < 4; ++mi)
#pragma unroll
            for (int r = 0; r < 4; ++r) {
                int grow = tm * 128 + wm * 64 + mi * 16 + lq * 4 + r;
                if (grow < count) {
                    int   tk = tokens_l[offs + grow];
                    float w  = gatew_l[offs + grow];
#pragma unroll
                    for (int ni = 0; ni < 4; ++ni) {
                        int gcol = tn * 128 + wn * 64 + ni * 16 + l16;
                        float v = (acc[mi][ni][r] + bias[e * NDIM + gcol]) * w;
                        atomicAdd(&out[(size_t)tk * DIM + gcol], v);
                    }
                }
            }
    }
}

extern "C" void kernel_launch(void* const* d_in, const int* in_sizes, int n_in,
                              void* d_out, int out_size, void* d_ws, size_t ws_size,
                              hipStream_t stream) {
    const float* x      = (const float*)d_in[0];
    const unsigned char* pm = (const unsigned char*)d_in[1];
    const float* gate_w = (const float*)d_in[2];
    const float* fc1_w  = (const float*)d_in[3];
    const float* fc1_b  = (const float*)d_in[4];
    const float* fc2_w  = (const float*)d_in[5];
    const float* fc2_b  = (const float*)d_in[6];

    float* out      = (float*)d_out;
    float* gate_out = out + (size_t)NTOK * DIM;
    float* loss_out = gate_out + (size_t)NTOK * NEXP;

    char* ws = (char*)d_ws;
    int*   counts   = (int*)ws;                 // 8
    int*   fill     = counts + 8;               // 8
    float* gv_sum   = (float*)(ws + 64);        // 8
    float* top1c    = (float*)(ws + 96);        // 8
    float* nt_acc   = (float*)(ws + 128);       // 1
    int*   offsets  = (int*)(ws + 160);         // 9
    int*   tokens_l = (int*)(ws + 256);         // CAP
    float* gatew_l  = (float*)(ws + 256 + CAP * 4);
    int*   tok_e    = (int*)(ws + 256 + CAP * 8);
    float* tok_w    = (float*)(ws + 256 + CAP * 8 + NTOK * 8);
    size_t off = 256 + (size_t)CAP * 8 + (size_t)NTOK * 16;   // 139,520
    u16* x_bf  = (u16*)(ws + off); off += (size_t)NTOK * DIM * 2;
    u16* w1_bf = (u16*)(ws + off); off += (size_t)NEXP * HDIM * DIM * 2;
    u16* w2_bf = (u16*)(ws + off); off += (size_t)NEXP * DIM * HDIM * 2;
    u16* act   = (u16*)(ws + off); off += (size_t)CAP * HDIM * 2;   // total ~113.4 MB

    // zero: control block + tokens_l + gatew_l (covers routing padding), and out
    hipMemsetAsync(ws, 0, 256 + (size_t)CAP * 8, stream);
    hipMemsetAsync(d_out, 0, (size_t)NTOK * DIM * 4, stream);

    cvt_kernel<<<2048, 256, 0, stream>>>(x,     x_bf,  NTOK * DIM / 8);
    cvt_kernel<<<4096, 256, 0, stream>>>(fc1_w, w1_bf, NEXP * HDIM * DIM / 8);
    cvt_kernel<<<4096, 256, 0, stream>>>(fc2_w, w2_bf, NEXP * DIM * HDIM / 8);

    gate_kernel<<<256, 256, 0, stream>>>(x, pm, gate_w, gate_out, tok_e, tok_w,
                                         counts, gv_sum, top1c, nt_acc);
    scan_loss_kernel<<<1, 64, 0, stream>>>(counts, offsets, gv_sum, top1c, nt_acc, loss_out);
    scatter_kernel<<<16, 256, 0, stream>>>(tok_e, tok_w, offsets, fill, tokens_l, gatew_l);

    dim3 g1(8 * 16, 32);   // x: expert(3 low bits) * tiles_n(2048/128); y: max tiles_m
    gemm_kernel<1, 1024, 2048, 1024><<<g1, 256, 0, stream>>>(
        x_bf, w1_bf, fc1_b, tokens_l, gatew_l, counts, offsets, act, nullptr);
    dim3 g2(8 * 8, 32);    // x: expert * tiles_n(1024/128)
    gemm_kernel<2, 2048, 1024, 2048><<<g2, 256, 0, stream>>>(
        act, w2_bf, fc2_b, tokens_l, gatew_l, counts, offsets, nullptr, out);
}

// Round 3
// 394.573 us; speedup vs baseline: 1.2579x; 1.2579x over previous
//
#include <hip/hip_runtime.h>

#define NTOK 4096
#define DIM  1024
#define NEXP 8
#define HDIM 2048
#define CAP  10240   // 2*NTOK assignments + 8*255 (256-alignment padding)

typedef unsigned short u16;
typedef __attribute__((ext_vector_type(8))) __bf16 bf16x8;
typedef __attribute__((ext_vector_type(4))) float  f32x4;
typedef __attribute__((ext_vector_type(8))) u16    u16x8;

__device__ inline u16 f2bf(float f) {
    union { float f; unsigned u; } v; v.f = f;
    unsigned r = v.u + 0x7fff + ((v.u >> 16) & 1);   // RNE
    return (u16)(r >> 16);
}

__device__ inline void gload_lds16(const void* g, void* l) {
    __builtin_amdgcn_global_load_lds(
        (const __attribute__((address_space(1))) unsigned int*)g,
        (__attribute__((address_space(3))) unsigned int*)l, 16, 0, 0);
}

// ---------------- fused fp32 -> bf16 convert: x, fc1_w, fc2_w in one pass ----------
__global__ __launch_bounds__(256) void cvt_all_kernel(
    const float* __restrict__ x, const float* __restrict__ w1, const float* __restrict__ w2,
    u16* __restrict__ x_bf, u16* __restrict__ w1_bf, u16* __restrict__ w2_bf) {
    const int C0 = NTOK * DIM / 8;
    const int C1 = NEXP * HDIM * DIM / 8;
    const int C2 = NEXP * DIM * HDIM / 8;
    int total = C0 + C1 + C2;
    int stride = gridDim.x * 256;
    for (int i = blockIdx.x * 256 + threadIdx.x; i < total; i += stride) {
        const float* src; u16* dst; int j;
        if (i < C0)            { src = x;  dst = x_bf;  j = i; }
        else if (i < C0 + C1)  { src = w1; dst = w1_bf; j = i - C0; }
        else                   { src = w2; dst = w2_bf; j = i - C0 - C1; }
        float4 a = ((const float4*)src)[(size_t)j * 2];
        float4 b = ((const float4*)src)[(size_t)j * 2 + 1];
        u16x8 v;
        v[0]=f2bf(a.x); v[1]=f2bf(a.y); v[2]=f2bf(a.z); v[3]=f2bf(a.w);
        v[4]=f2bf(b.x); v[5]=f2bf(b.y); v[6]=f2bf(b.z); v[7]=f2bf(b.w);
        ((u16x8*)dst)[j] = v;
    }
}

// ---------------- gate: fp32 logits, softmax, top2, loss partials ----------------
__global__ __launch_bounds__(256) void gate_kernel(
    const float* __restrict__ x, const unsigned char* __restrict__ pm,
    const float* __restrict__ gw, float* __restrict__ gate_out,
    int* __restrict__ tok_e, float* __restrict__ tok_w,
    int* __restrict__ counts, float* __restrict__ gv_sum,
    float* __restrict__ top1c, float* __restrict__ nt_acc) {
    __shared__ float lgw[NEXP * DIM];
    __shared__ float bgv[NEXP];
    __shared__ float bt1[NEXP];
    __shared__ int   bcnt[NEXP];
    __shared__ float bnt;
    int t = threadIdx.x;
    for (int k = t; k < NEXP * DIM / 4; k += 256)
        ((float4*)lgw)[k] = ((const float4*)gw)[k];
    if (t < NEXP) { bgv[t] = 0.f; bt1[t] = 0.f; bcnt[t] = 0; }
    if (t == 0) bnt = 0.f;
    __syncthreads();

    int lane = t & 63, wv = t >> 6;
    for (int i = 0; i < 4; ++i) {
        int tok = blockIdx.x * 16 + wv * 4 + i;
        float acc[NEXP];
#pragma unroll
        for (int e = 0; e < NEXP; ++e) acc[e] = 0.f;
        const float* xr = x + (size_t)tok * DIM;
        for (int j = lane; j < DIM; j += 64) {
            float xv = xr[j];
#pragma unroll
            for (int e = 0; e < NEXP; ++e) acc[e] += xv * lgw[e * DIM + j];
        }
#pragma unroll
        for (int e = 0; e < NEXP; ++e) {
            float s = acc[e];
            for (int off = 1; off < 64; off <<= 1) s += __shfl_xor(s, off);
            acc[e] = s;
        }
        if (lane == 0) {
            bool padded = pm[tok] != 0;
            float m = acc[0];
            for (int e = 1; e < NEXP; ++e) m = fmaxf(m, acc[e]);
            float ex[NEXP]; float ssum = 0.f;
            for (int e = 0; e < NEXP; ++e) { ex[e] = expf(acc[e] - m); ssum += ex[e]; }
            float inv = 1.f / ssum;
            float gv[NEXP];
            for (int e = 0; e < NEXP; ++e) gv[e] = padded ? 0.f : ex[e] * inv;
            for (int e = 0; e < NEXP; ++e) gate_out[(size_t)tok * NEXP + e] = gv[e];
            int t1 = 0;
            for (int e = 1; e < NEXP; ++e) if (gv[e] > gv[t1]) t1 = e;
            int t2 = (t1 == 0) ? 1 : 0;
            for (int e = 0; e < NEXP; ++e) { if (e == t1 || e == t2) continue; if (gv[e] > gv[t2]) t2 = e; }
            float w1 = gv[t1], w2 = gv[t2], den = w1 + w2;
            float invd = (den > 0.f) ? 1.f / den : 0.f;
            tok_e[tok * 2]     = t1;  tok_e[tok * 2 + 1] = t2;
            tok_w[tok * 2]     = w1 * invd;
            tok_w[tok * 2 + 1] = w2 * invd;
            atomicAdd(&bcnt[t1], 1); atomicAdd(&bcnt[t2], 1);
            if (!padded) {
                atomicAdd(&bt1[t1], 1.f); atomicAdd(&bnt, 1.f);
                for (int e = 0; e < NEXP; ++e) atomicAdd(&bgv[e], gv[e]);
            }
        }
    }
    __syncthreads();
    if (t < NEXP) {
        atomicAdd(&counts[t], bcnt[t]);
        atomicAdd(&gv_sum[t], bgv[t]);
        atomicAdd(&top1c[t],  bt1[t]);
    }
    if (t == 0) atomicAdd(nt_acc, bnt);
}

// scan (256-aligned expert offsets) + lb_loss
__global__ void scan_loss_kernel(const int* __restrict__ counts, int* __restrict__ offsets,
                                 const float* __restrict__ gv_sum, const float* __restrict__ top1c,
                                 const float* __restrict__ nt_acc, float* __restrict__ lout) {
    if (threadIdx.x == 0 && blockIdx.x == 0) {
        int o = 0;
        for (int e = 0; e < NEXP; ++e) { offsets[e] = o; o += (counts[e] + 255) & ~255; }
        offsets[NEXP] = o;
        float nt = nt_acc[0];
        if (nt <= 0.f) nt = 1.f;
        float s = 0.f;
        for (int e = 0; e < NEXP; ++e) s += top1c[e] * gv_sum[e];
        lout[0] = NEXP * s / (nt * nt);
    }
}

__global__ __launch_bounds__(256) void scatter_kernel(
    const int* __restrict__ tok_e, const float* __restrict__ tok_w,
    const int* __restrict__ offsets, int* __restrict__ fill,
    int* __restrict__ tokens_l, float* __restrict__ gatew_l, int* __restrict__ pos_of) {
    int tok = blockIdx.x * 256 + threadIdx.x;
    if (tok >= NTOK) return;
    for (int k = 0; k < 2; ++k) {
        int e = tok_e[tok * 2 + k];
        int p = atomicAdd(&fill[e], 1);
        int pos = offsets[e] + p;
        tokens_l[pos] = tok;
        gatew_l[pos]  = tok_w[tok * 2 + k];
        pos_of[tok * 2 + k] = pos;
    }
}

// ---------------- grouped GEMM: BM=256 BN=128 BK=64, 8 waves (4Mx2N, 64x64/wave),
// 3-buffer LDS pipeline with counted vmcnt (never 0 in main loop) + raw s_barrier.
// XOR swizzle: LDS stores Global[row][slot^(row&7)] at linear slot (pre-swizzled
// global source, linear gload_lds dest); ds_read applies same XOR. 16-way -> floor.
// EPI=1: act = relu(Agath @ B^T + bias) bf16      (K=1024, N=2048)
// EPI=2: y_part[pos] = gatew * (A @ B^T + bias)   (K=2048, N=1024), combined later
template <int EPI, int KDIM, int NDIM, int ASTRIDE>
__global__ __launch_bounds__(512, 2) void gemm_kernel(
    const u16* __restrict__ A, const u16* __restrict__ Bw,
    const float* __restrict__ bias,
    const int* __restrict__ tokens_l, const float* __restrict__ gatew_l,
    const int* __restrict__ counts, const int* __restrict__ offsets,
    u16* __restrict__ actout, float* __restrict__ yout) {
    int e  = blockIdx.x & 7;          // expert in low bits -> per-XCD L2 residency
    int tn = blockIdx.x >> 3;
    int tm = blockIdx.y;
    int count = counts[e];
    if (tm * 256 >= count) return;
    int offs = offsets[e];

    __shared__ __align__(16) u16 lds[3 * 24576];   // 3 x (A 256x64 + B 128x64) = 144 KB

    int t = threadIdx.x;
    int tr8 = t >> 3, c8 = t & 7;
    int sc8 = c8 ^ (tr8 & 7);          // inverse-swizzled source slot
    const u16* Ap[4]; const u16* Bp[2];
#pragma unroll
    for (int l = 0; l < 4; ++l) {
        int row = l * 64 + tr8;        // 0..255
        size_t arow = (EPI == 1) ? (size_t)tokens_l[offs + tm * 256 + row]
                                 : (size_t)(offs + tm * 256 + row);
        Ap[l] = A + arow * ASTRIDE + sc8 * 8;
    }
#pragma unroll
    for (int l = 0; l < 2; ++l) {
        int row = l * 64 + tr8;        // 0..127
        Bp[l] = Bw + ((size_t)e * NDIM + tn * 128 + row) * (size_t)KDIM + sc8 * 8;
    }

    f32x4 acc[4][4];
#pragma unroll
    for (int i = 0; i < 4; ++i)
#pragma unroll
        for (int j = 0; j < 4; ++j) acc[i][j] = (f32x4)(0.f);

    int lane = t & 63, w = t >> 6;
    int wr = w >> 1, wc = w & 1;       // 4M x 2N wave grid
    int l16 = lane & 15, lq = lane >> 4, rx = l16 & 7;

    auto STAGE = [&](int kt, int buf) {   // 6 x gload_lds16 per thread (A:4, B:2)
        u16* b0 = &lds[buf * 24576];
#pragma unroll
        for (int l = 0; l < 4; ++l)
            gload_lds16(Ap[l] + kt * 64, b0 + (l * 512 + t) * 8);
#pragma unroll
        for (int l = 0; l < 2; ++l)
            gload_lds16(Bp[l] + kt * 64, b0 + 16384 + (l * 512 + t) * 8);
    };

    const int NKT = KDIM / 64;
    STAGE(0, 0);
    STAGE(1, 1);

    int cb = 0, sb = 2;
#pragma unroll 1
    for (int kt = 0; kt < NKT; ++kt) {
        if (kt + 2 < NKT) {
            STAGE(kt + 2, sb);
            sb = (sb == 2) ? 0 : sb + 1;
            asm volatile("s_waitcnt vmcnt(12)" ::: "memory");  // tile kt landed; 2 in flight
        } else if (kt + 1 < NKT) {
            asm volatile("s_waitcnt vmcnt(6)" ::: "memory");
        } else {
            asm volatile("s_waitcnt vmcnt(0)" ::: "memory");
        }
        __builtin_amdgcn_s_barrier();
        asm volatile("" ::: "memory");
        const u16* LA = &lds[cb * 24576];
        const u16* LB = &lds[cb * 24576 + 16384];
        __builtin_amdgcn_s_setprio(1);
#pragma unroll
        for (int kk = 0; kk < 2; ++kk) {
            bf16x8 av[4], bv[4];
#pragma unroll
            for (int mi = 0; mi < 4; ++mi)
                av[mi] = *(const bf16x8*)&LA[(wr * 64 + mi * 16 + l16) * 64 + (((kk * 4 + lq) ^ rx) * 8)];
#pragma unroll
            for (int ni = 0; ni < 4; ++ni)
                bv[ni] = *(const bf16x8*)&LB[(wc * 64 + ni * 16 + l16) * 64 + (((kk * 4 + lq) ^ rx) * 8)];
#pragma unroll
            for (int mi = 0; mi < 4; ++mi)
#pragma unroll
                for (int ni = 0; ni < 4; ++ni)
                    acc[mi][ni] = __builtin_amdgcn_mfma_f32_16x16x32_bf16(av[mi], bv[ni], acc[mi][ni], 0, 0, 0);
        }
        __builtin_amdgcn_s_setprio(0);
        asm volatile("" ::: "memory");
        __builtin_amdgcn_s_barrier();
        asm volatile("" ::: "memory");
        cb = (cb == 2) ? 0 : cb + 1;
    }

    if (EPI == 1) {
#pragma unroll
        for (int ni = 0; ni < 4; ++ni) {
            int col = tn * 128 + wc * 64 + ni * 16 + l16;
            float bb = bias[e * NDIM + col];
#pragma unroll
            for (int mi = 0; mi < 4; ++mi)
#pragma unroll
                for (int r = 0; r < 4; ++r) {
                    int row = tm * 256 + wr * 64 + mi * 16 + lq * 4 + r;
                    actout[(size_t)(offs + row) * HDIM + col] = f2bf(fmaxf(acc[mi][ni][r] + bb, 0.f));
                }
        }
    } else {
#pragma unroll
        for (int mi = 0; mi < 4; ++mi)
#pragma unroll
            for (int r = 0; r < 4; ++r) {
                int row = tm * 256 + wr * 64 + mi * 16 + lq * 4 + r;
                float gw_ = gatew_l[offs + row];   // 0 for padding rows (memset)
#pragma unroll
                for (int ni = 0; ni < 4; ++ni) {
                    int col = tn * 128 + wc * 64 + ni * 16 + l16;
                    yout[(size_t)(offs + row) * NDIM + col] = (acc[mi][ni][r] + bias[e * NDIM + col]) * gw_;
                }
            }
    }
}

// out[tok] = y_part[pos1] + y_part[pos2]   (gate weights already applied)
__global__ __launch_bounds__(256) void combine_kernel(
    const float* __restrict__ y, const int* __restrict__ pos_of, float* __restrict__ out) {
    int stride = gridDim.x * 256;
    for (int idx = blockIdx.x * 256 + threadIdx.x; idx < NTOK * DIM / 4; idx += stride) {
        int tok = idx >> 8;            // DIM/4 = 256 float4 per row
        int c4  = idx & 255;
        int p1 = pos_of[tok * 2], p2 = pos_of[tok * 2 + 1];
        float4 a = ((const float4*)y)[(size_t)p1 * 256 + c4];
        float4 b = ((const float4*)y)[(size_t)p2 * 256 + c4];
        float4 o; o.x = a.x + b.x; o.y = a.y + b.y; o.z = a.z + b.z; o.w = a.w + b.w;
        ((float4*)out)[idx] = o;
    }
}

extern "C" void kernel_launch(void* const* d_in, const int* in_sizes, int n_in,
                              void* d_out, int out_size, void* d_ws, size_t ws_size,
                              hipStream_t stream) {
    const float* x      = (const float*)d_in[0];
    const unsigned char* pm = (const unsigned char*)d_in[1];
    const float* gate_w = (const float*)d_in[2];
    const float* fc1_w  = (const float*)d_in[3];
    const float* fc1_b  = (const float*)d_in[4];
    const float* fc2_w  = (const float*)d_in[5];
    const float* fc2_b  = (const float*)d_in[6];

    float* out      = (float*)d_out;
    float* gate_out = out + (size_t)NTOK * DIM;
    float* loss_out = gate_out + (size_t)NTOK * NEXP;

    char* ws = (char*)d_ws;
    int*   counts   = (int*)ws;                          // 8
    int*   fill     = (int*)(ws + 32);                   // 8
    float* gv_sum   = (float*)(ws + 64);                 // 8
    float* top1c    = (float*)(ws + 96);                 // 8
    float* nt_acc   = (float*)(ws + 128);                // 1
    int*   offsets  = (int*)(ws + 160);                  // 9
    int*   tokens_l = (int*)(ws + 256);                  // CAP
    float* gatew_l  = (float*)(ws + 256 + CAP * 4);      // CAP
    int*   tok_e    = (int*)(ws + 256 + CAP * 8);        // 2*NTOK
    float* tok_w    = (float*)(ws + 256 + CAP * 8 + NTOK * 8);
    int*   pos_of   = (int*)(ws + 256 + CAP * 8 + NTOK * 16);
    size_t off = 256 + (size_t)CAP * 8 + (size_t)NTOK * 24;      // 180,480
    u16* x_bf  = (u16*)(ws + off);                       // 8.39 MB
    float* y_part = (float*)(ws + off);                  // aliases x_bf..w1_bf (40 MB, gemm2 phase)
    off += (size_t)NTOK * DIM * 2;
    u16* w1_bf = (u16*)(ws + off); off += (size_t)NEXP * HDIM * DIM * 2;   // 33.6 MB
    u16* w2_bf = (u16*)(ws + off); off += (size_t)NEXP * DIM * HDIM * 2;   // 33.6 MB
    u16* act   = (u16*)(ws + off); off += (size_t)CAP * HDIM * 2;          // 41.9 MB -> ~112 MB total

    hipMemsetAsync(ws, 0, 256 + (size_t)CAP * 8, stream);   // ctrl + tokens_l + gatew_l

    cvt_all_kernel<<<2048, 256, 0, stream>>>(x, fc1_w, fc2_w, x_bf, w1_bf, w2_bf);

    gate_kernel<<<256, 256, 0, stream>>>(x, pm, gate_w, gate_out, tok_e, tok_w,
                                         counts, gv_sum, top1c, nt_acc);
    scan_loss_kernel<<<1, 64, 0, stream>>>(counts, offsets, gv_sum, top1c, nt_acc, loss_out);
    scatter_kernel<<<16, 256, 0, stream>>>(tok_e, tok_w, offsets, fill,
                                           tokens_l, gatew_l, pos_of);

    dim3 g1(8 * 16, 8);   // x: expert(3 low bits) * tiles_n(2048/128); y: m-tiles of 256
    gemm_kernel<1, 1024, 2048, 1024><<<g1, 512, 0, stream>>>(
        x_bf, w1_bf, fc1_b, tokens_l, gatew_l, counts, offsets, act, nullptr);
    dim3 g2(8 * 8, 8);    // x: expert * tiles_n(1024/128)
    gemm_kernel<2, 2048, 1024, 2048><<<g2, 512, 0, stream>>>(
        act, w2_bf, fc2_b, tokens_l, gatew_l, counts, offsets, nullptr, y_part);

    combine_kernel<<<2048, 256, 0, stream>>>(y_part, pos_of, out);
}